// Round 4
// baseline (273.052 us; speedup 1.0000x reference)
//
#include <hip/hip_runtime.h>
#include <hip/hip_bf16.h>
#include <math.h>

// Fused SelfAttention (attention over the HEADS axis, per token):
//   qkv = v @ [Wq|Wk|Wv]  (65536x256 @ 256x768, f16 MFMA)
//   per-token 8x8 softmax attention over heads (packed f16 + fp32 softmax)
//   out = x @ Wp + bp       (65536x256 @ 256x256, f16 MFMA)
//
// MFMA orientation: D = A*B, A = W^T-tile (rows = output col n), B = v^T-tile
// (cols = tokens). C/D layout: col(lane&15)=token, row(quad*4+r)=n.
//
// R8: model = GEMMs are weight-VMEM-bound (1 KB A-frag feeds TM/16 MFMAs;
// R7's 2x weight stream cost +7us, R6's 4-rows/frag is the best ratio).
//  - GEMM1: R6 tiling kept (3 tiles x 4 tt, 256 B/MFMA VMEM).
//  - GEMM2: j-split (i=w>>1 owns Wp tiles {2i,2i+1}; jj=w&1 owns 2 token
//    rows) -> 2 xf ds_reads + 2 W-loads per 4 MFMAs (256 B/MFMA both
//    streams; was 1 KB/MFMA LDS).
//  - Persistent blocks: grid=256 (1/CU), GITER=4 tiles of 64 tokens.
//    Pipeline across tiles: v(g+1) global loads issue before attention,
//    LDS-write after barrier-4 (vv-section dead then); G2(g) and G1(g+1)
//    merge with no barrier between (G1 reads only v(g+1), fenced by b5);
//    G1 ring re-primes mid-G2. 4 barriers/tile, no exposed HBM latency.
//  - v input staged in vv-section [512,768): all G1 writebacks uniform
//    post-b7 (no immediate/deferred split). x -> [0,256) as before.

#define DIMX      256
#define NH        8
#define HD        32
#define TM        64       // tokens per tile-iteration
#define GITER     4        // tiles per persistent block
#define NTHREADS  1024     // 16 waves
#define QSTRIDE   776      // f16 units per row; 1552 B (16B aligned)
#define KT        8        // 256/32 k-tiles
#define NT_QKV    48       // q: 0..15, k: 16..31, v: 32..47

typedef _Float16 f16x8 __attribute__((ext_vector_type(8)));
typedef _Float16 f16x4 __attribute__((ext_vector_type(4)));
typedef _Float16 f16x2 __attribute__((ext_vector_type(2)));
typedef float    f32x4 __attribute__((ext_vector_type(4)));

static __device__ __forceinline__ f16x2 pkrtz(float a, float b) {
    return (f16x2)__builtin_amdgcn_cvt_pkrtz(a, b);
}

// ---------------------------------------------------------------------------
// Prep: pack Wq|Wk|Wv and Wp into MFMA A-operand fragment order, fp32->f16.
// frag[j] = W[kt*32 + quad*8 + j][nt*16 + (lane&15)]
// packed index u = (nt*KT + kt)*64 + lane ; 8 f16 (16 B) per u, contiguous.
// ---------------------------------------------------------------------------
__global__ void pack_weights(const float* __restrict__ Wq,
                             const float* __restrict__ Wk,
                             const float* __restrict__ Wv,
                             const float* __restrict__ Wp,
                             _Float16* __restrict__ pk)
{
    const int QKV_FRAGS = NT_QKV * KT * 64;   // 24576
    int u = blockIdx.x * blockDim.x + threadIdx.x;  // 0..32767
    const float* W;
    int nt, kt, lane;
    if (u < QKV_FRAGS) {
        nt = u / (KT * 64); kt = (u / 64) % KT; lane = u % 64;
        if (nt < 16)      { W = Wq; }
        else if (nt < 32) { W = Wk; nt -= 16; }
        else              { W = Wv; nt -= 32; }
    } else {
        int u2 = u - QKV_FRAGS;
        nt = u2 / (KT * 64); kt = (u2 / 64) % KT; lane = u2 % 64;
        W = Wp;
    }
    const int n  = nt * 16 + (lane & 15);
    const int k0 = kt * 32 + (lane >> 4) * 8;
    f16x8 frag;
#pragma unroll
    for (int j = 0; j < 8; ++j)
        frag[j] = (_Float16)W[(size_t)(k0 + j) * DIMX + n];
    *(f16x8*)(pk + (size_t)u * 8) = frag;
}

// ---------------------------------------------------------------------------
// Main fused persistent kernel. LDS: single 64x776 f16 region (99,328 B).
// Stationary layout per tile-iter: v-input staged in cols [512,768);
// q|k|vv outputs -> [0,256)|[256,512)|[512,768); x overwrites [0,256).
// ---------------------------------------------------------------------------
__global__ __launch_bounds__(NTHREADS, 4)   // 16 waves = 4/EU, 1 block/CU
void fused_attn_mfma(const float* __restrict__ v,
                     const _Float16* __restrict__ Wqkv_pk,
                     const _Float16* __restrict__ Wp_pk,
                     const float* __restrict__ bp,
                     float* __restrict__ out)
{
    __shared__ __align__(16) _Float16 S[TM * QSTRIDE];   // 99,328 B

    const int tid   = threadIdx.x;
    const int lane  = tid & 63;
    const int wv_id = tid >> 6;      // wave 0..15
    const int l15   = lane & 15;
    const int quad  = lane >> 4;
    const int t3    = 3 * wv_id;     // GEMM1 tiles {t3, t3+1, t3+2}
    const int i2    = wv_id >> 1;    // GEMM2 tile-set: Wp tiles {2*i2, 2*i2+1}
    const int jj    = wv_id & 1;     // GEMM2 token half: rows [jj*32, jj*32+32)

    const long blk0 = (long)blockIdx.x * (GITER * TM);

    const f16x8* wbA = (const f16x8*)Wqkv_pk + lane;
    const f16x8* wbB = (const f16x8*)Wp_pk + lane;
    f16x8 Wr[8];    // GEMM1 ring-8; consume order u = kt*3 + j
    f16x8 W2[4];    // GEMM2 ring-4; consume order u2 = kt*2 + jx

    // ---- entry: stage v(0) into vv-section + prime GEMM1 ring --------------
    {
        const float4* src = (const float4*)(v + blk0 * DIMX);
        float4 t4[4];
#pragma unroll
        for (int i = 0; i < 4; ++i)
            t4[i] = src[tid + NTHREADS * i];
#pragma unroll
        for (int p = 0; p < 8; ++p)
            Wr[p] = wbA[(size_t)((t3 + p % 3) * KT + p / 3) * 64];
#pragma unroll
        for (int i = 0; i < 4; ++i) {
            int u = tid + NTHREADS * i;       // 0..4095 float4 slots
            int m = u >> 6;                   // token row
            int c = (u & 63) * 4;
            f16x2 lo = pkrtz(t4[i].x, t4[i].y), hi = pkrtz(t4[i].z, t4[i].w);
            f16x4 b4 = { lo.x, lo.y, hi.x, hi.y };
            *(f16x4*)&S[m * QSTRIDE + 512 + c] = b4;
        }
        __syncthreads();   // v(0) visible
    }

#pragma unroll 1   // keep runtime loop: no cross-iter CSE of weight loads
    for (int g = 0; g < GITER; ++g) {
        const long token0 = blk0 + (long)g * TM;

        // ---- GEMM1: 3 tiles x 4 tt, B from vv-section, ring-8 weights ------
        f32x4 acc[3][4];
#pragma unroll
        for (int j = 0; j < 3; ++j)
#pragma unroll
            for (int tt = 0; tt < 4; ++tt)
                acc[j][tt] = (f32x4){0.f, 0.f, 0.f, 0.f};

#pragma unroll
        for (int kt = 0; kt < KT; ++kt) {
            f16x8 vf[4];
#pragma unroll
            for (int tt = 0; tt < 4; ++tt)
                vf[tt] = *(const f16x8*)&S[(tt * 16 + l15) * QSTRIDE + 512 + kt * 32 + quad * 8];
#pragma unroll
            for (int j = 0; j < 3; ++j) {
                const int u = kt * 3 + j;
                f16x8 w = Wr[u & 7];
                if (u + 8 < 24) {
                    const int un = u + 8;       // compile-time
                    Wr[u & 7] = wbA[(size_t)((t3 + un % 3) * KT + un / 3) * 64];
                }
#pragma unroll
                for (int tt = 0; tt < 4; ++tt)
                    acc[j][tt] = __builtin_amdgcn_mfma_f32_16x16x32_f16(w, vf[tt], acc[j][tt], 0, 0, 0);
            }
        }
        __syncthreads();   // b7: all vf reads done; entire S writable

        // writeback q|k|vv tiles (uniform, post-b7)
#pragma unroll
        for (int j = 0; j < 3; ++j)
#pragma unroll
            for (int tt = 0; tt < 4; ++tt) {
                f16x2 a = pkrtz(acc[j][tt][0], acc[j][tt][1]);
                f16x2 b = pkrtz(acc[j][tt][2], acc[j][tt][3]);
                f16x4 p4 = { a.x, a.y, b.x, b.y };
                *(f16x4*)&S[(tt * 16 + l15) * QSTRIDE + (t3 + j) * 16 + quad * 4] = p4;
            }
        __syncthreads();   // b8: q|k|vv complete

        // ---- early VMEM: v(g+1) global loads + GEMM2 ring prime ------------
        float4 t4[4];
        if (g + 1 < GITER) {
            const float4* srcn = (const float4*)(v + (token0 + TM) * DIMX);
#pragma unroll
            for (int i = 0; i < 4; ++i)
                t4[i] = srcn[tid + NTHREADS * i];
        }
#pragma unroll
        for (int p = 0; p < 4; ++p)
            W2[p] = wbB[(size_t)((2 * i2 + (p & 1)) * KT + (p >> 1)) * 64];

        // ---- attention: 16 threads/token = (head h, half d0) ---------------
        {
            const int ta  = tid >> 4;         // token 0..63
            const int sub = tid & 15;
            const int h   = sub >> 1;
            const int d0  = (sub & 1) * 16;
            const float scale = 0.17677669529663687f;  // 32^-0.5

            const _Float16* qrow  = &S[ta * QSTRIDE + h * HD + d0];
            const _Float16* kbase = &S[ta * QSTRIDE + 256 + d0];
            const _Float16* vbase = &S[ta * QSTRIDE + 512 + d0];

            f16x8 q0 = *(const f16x8*)qrow;
            f16x8 q1 = *(const f16x8*)(qrow + 8);

            float logits[NH];
#pragma unroll
            for (int g2 = 0; g2 < NH; ++g2) {
                f16x8 k0 = *(const f16x8*)(kbase + g2 * HD);
                f16x8 k1 = *(const f16x8*)(kbase + g2 * HD + 8);
                f16x8 p  = q0 * k0;
                p += q1 * k1;
                f16x4 r4 = __builtin_shufflevector(p, p, 0, 1, 2, 3)
                         + __builtin_shufflevector(p, p, 4, 5, 6, 7);
                f16x2 r2 = __builtin_shufflevector(r4, r4, 0, 1)
                         + __builtin_shufflevector(r4, r4, 2, 3);
                logits[g2] = (float)r2.x + (float)r2.y;
            }
#pragma unroll
            for (int g2 = 0; g2 < NH; ++g2)
                logits[g2] = (logits[g2] + __shfl_xor(logits[g2], 1, 64)) * scale;

            float mx = logits[0];
#pragma unroll
            for (int g2 = 1; g2 < NH; ++g2) mx = fmaxf(mx, logits[g2]);
            float se = 0.f;
#pragma unroll
            for (int g2 = 0; g2 < NH; ++g2) { logits[g2] = __expf(logits[g2] - mx); se += logits[g2]; }
            float inv = 1.f / se;

            f16x8 xa0 = (f16x8)(_Float16)0.f;
            f16x8 xa1 = (f16x8)(_Float16)0.f;
#pragma unroll
            for (int g2 = 0; g2 < NH; ++g2) {
                _Float16 ph = (_Float16)(logits[g2] * inv);
                f16x8 pw = { ph, ph, ph, ph, ph, ph, ph, ph };
                f16x8 v0 = *(const f16x8*)(vbase + g2 * HD);
                f16x8 v1 = *(const f16x8*)(vbase + g2 * HD + 8);
                xa0 += pw * v0;
                xa1 += pw * v1;
            }
            __syncthreads();   // b4: all q/k/vv reads done
            *(f16x8*)&S[ta * QSTRIDE + h * HD + d0]     = xa0;
            *(f16x8*)&S[ta * QSTRIDE + h * HD + d0 + 8] = xa1;
        }

        // v(g+1) -> vv-section (dead after b4)
        if (g + 1 < GITER) {
#pragma unroll
            for (int i = 0; i < 4; ++i) {
                int u = tid + NTHREADS * i;
                int m = u >> 6;
                int c = (u & 63) * 4;
                f16x2 lo = pkrtz(t4[i].x, t4[i].y), hi = pkrtz(t4[i].z, t4[i].w);
                f16x4 b4v = { lo.x, lo.y, hi.x, hi.y };
                *(f16x4*)&S[m * QSTRIDE + 512 + c] = b4v;
            }
        }
        __syncthreads();   // b5: x + v(g+1) complete

        // ---- GEMM2: out = x @ Wp + bp; j-split (2 xf + 2 W per 4 MFMA) -----
        {
            f32x4 acc2[2][2];   // [jx][tt]
#pragma unroll
            for (int jx = 0; jx < 2; ++jx)
#pragma unroll
                for (int tt = 0; tt < 2; ++tt)
                    acc2[jx][tt] = (f32x4){0.f, 0.f, 0.f, 0.f};

#pragma unroll
            for (int kt = 0; kt < KT; ++kt) {
                f16x8 xf[2];
#pragma unroll
                for (int tt = 0; tt < 2; ++tt)
                    xf[tt] = *(const f16x8*)&S[(jj * 32 + tt * 16 + l15) * QSTRIDE + kt * 32 + quad * 8];
#pragma unroll
                for (int jx = 0; jx < 2; ++jx) {
                    const int u2 = kt * 2 + jx;
                    f16x8 w = W2[u2 & 3];
                    if (u2 + 4 < 16)
                        W2[u2 & 3] = wbB[(size_t)((2 * i2 + jx) * KT + (kt + 2)) * 64];
                    acc2[jx][0] = __builtin_amdgcn_mfma_f32_16x16x32_f16(w, xf[0], acc2[jx][0], 0, 0, 0);
                    acc2[jx][1] = __builtin_amdgcn_mfma_f32_16x16x32_f16(w, xf[1], acc2[jx][1], 0, 0, 0);
                }
                if (kt == 4 && g + 1 < GITER) {   // re-prime GEMM1 ring for g+1
#pragma unroll
                    for (int p = 0; p < 8; ++p)
                        Wr[p] = wbA[(size_t)((t3 + p % 3) * KT + p / 3) * 64];
                }
            }

#pragma unroll
            for (int jx = 0; jx < 2; ++jx) {
                f32x4 b = *(const f32x4*)&bp[(2 * i2 + jx) * 16 + quad * 4];
#pragma unroll
                for (int tt = 0; tt < 2; ++tt) {
                    f32x4 o = acc2[jx][tt] + b;
                    *(f32x4*)&out[(token0 + jj * 32 + tt * 16 + l15) * DIMX + (2 * i2 + jx) * 16 + quad * 4] = o;
                }
            }
        }
        // no barrier: G1(g+1) reads only vv-section (fenced by b5) and its
        // writebacks wait at b7, which also fences this iter's x reads.
    }
}

extern "C" void kernel_launch(void* const* d_in, const int* in_sizes, int n_in,
                              void* d_out, int out_size, void* d_ws, size_t ws_size,
                              hipStream_t stream) {
    const float* v  = (const float*)d_in[0];
    const float* Wq = (const float*)d_in[1];
    const float* Wk = (const float*)d_in[2];
    const float* Wv = (const float*)d_in[3];
    const float* Wp = (const float*)d_in[4];
    const float* bp = (const float*)d_in[5];
    float* out = (float*)d_out;

    _Float16* pk = (_Float16*)d_ws;                // 32768 frags * 16 B = 512 KB
    const _Float16* Wqkv_pk = pk;                  // 24576 frags
    const _Float16* Wp_pk   = pk + (size_t)24576 * 8;

    pack_weights<<<256, 128, 0, stream>>>(Wq, Wk, Wv, Wp, pk);

    const int ntokens = in_sizes[0] / DIMX;        // 65536
    fused_attn_mfma<<<ntokens / (TM * GITER), NTHREADS, 0, stream>>>(v, Wqkv_pk, Wp_pk, bp, out);
}

// Round 5
// 154.861 us; speedup vs baseline: 1.7632x; 1.7632x over previous
//
#include <hip/hip_runtime.h>
#include <hip/hip_bf16.h>
#include <math.h>

// Fused SelfAttention (attention over the HEADS axis, per token):
//   qkv = v @ [Wq|Wk|Wv]  (65536x256 @ 256x768, f16 MFMA)
//   per-token 8x8 softmax attention over heads (packed f16 + fp32 softmax)
//   out = x @ Wp + bp       (65536x256 @ 256x256, f16 MFMA)
//
// MFMA orientation: D = A*B, A = W^T-tile (rows = output col n), B = v^T-tile
// (cols = tokens). C/D layout: col(lane&15)=token, row(quad*4+r)=n.
//
// R9: register-cap law from R4-R8: 24 waves/CU <=> <=64 combined regs (R4 sat
// exactly at it: 40V+24A); 16 waves <=> <=128. launch_bounds 2nd arg behaves
// as min-BLOCKS/CU (CUDA semantics), clamped at 32 waves.
//  - TM=48, 512 thr, LDS 74.5 KB -> 2 blocks/CU (keeps R4's independent-block
//    overlap, unlike R6's 1/CU) with 2/3 of R4's L2 weight traffic (~700 MB).
//  - bounds(512,2) -> 128-reg budget; spent on lead-2 weight prefetch
//    (wA/wB/wC 3-stage, ~2 iters of lead) in both GEMM1 passes and GEMM2.
//    Budget in G1: 36 acc + 36 ring + 12 vf + ~15 addr ~= 100 <= 128.
//  - attention: 8 threads/token (sub = head), fully thread-local softmax
//    (no shfl); 384/512 threads active; barriers hoisted out of the guard.
//  - tail block (65536 = 1365*48 + 16): zero-fill staging, guard out stores.

#define DIMX      256
#define NH        8
#define HD        32
#define TM        48       // tokens per block
#define NTHREADS  512      // 8 waves
#define QSTRIDE   776      // f16 units per row; 1552 B (row shift = 97 16B-slots, odd -> conflict-free b128)
#define KT        8        // 256/32 k-tiles
#define NT_QKV    48       // q: 0..15, k: 16..31, v: 32..47

typedef _Float16 f16x8 __attribute__((ext_vector_type(8)));
typedef _Float16 f16x4 __attribute__((ext_vector_type(4)));
typedef _Float16 f16x2 __attribute__((ext_vector_type(2)));
typedef float    f32x4 __attribute__((ext_vector_type(4)));

static __device__ __forceinline__ f16x2 pkrtz(float a, float b) {
    return (f16x2)__builtin_amdgcn_cvt_pkrtz(a, b);
}

// ---------------------------------------------------------------------------
// Prep: pack Wq|Wk|Wv and Wp into MFMA A-operand fragment order, fp32->f16.
// frag[j] = W[kt*32 + quad*8 + j][nt*16 + (lane&15)]
// packed index u = (nt*KT + kt)*64 + lane ; 8 f16 (16 B) per u, contiguous.
// ---------------------------------------------------------------------------
__global__ void pack_weights(const float* __restrict__ Wq,
                             const float* __restrict__ Wk,
                             const float* __restrict__ Wv,
                             const float* __restrict__ Wp,
                             _Float16* __restrict__ pk)
{
    const int QKV_FRAGS = NT_QKV * KT * 64;   // 24576
    int u = blockIdx.x * blockDim.x + threadIdx.x;  // 0..32767
    const float* W;
    int nt, kt, lane;
    if (u < QKV_FRAGS) {
        nt = u / (KT * 64); kt = (u / 64) % KT; lane = u % 64;
        if (nt < 16)      { W = Wq; }
        else if (nt < 32) { W = Wk; nt -= 16; }
        else              { W = Wv; nt -= 32; }
    } else {
        int u2 = u - QKV_FRAGS;
        nt = u2 / (KT * 64); kt = (u2 / 64) % KT; lane = u2 % 64;
        W = Wp;
    }
    const int n  = nt * 16 + (lane & 15);
    const int k0 = kt * 32 + (lane >> 4) * 8;
    f16x8 frag;
#pragma unroll
    for (int j = 0; j < 8; ++j)
        frag[j] = (_Float16)W[(size_t)(k0 + j) * DIMX + n];
    *(f16x8*)(pk + (size_t)u * 8) = frag;
}

// ---------------------------------------------------------------------------
// Main fused kernel. LDS: single 48x776 f16 region (74,496 B -> 2 blocks/CU).
//   phase A: v tile in cols [0,256); phase B: q|k|vv in cols [0,768);
//   phase C: x tile overwrites q-section cols [0,256).
// ---------------------------------------------------------------------------
__global__ __launch_bounds__(NTHREADS, 2)   // 2 blocks/CU, 16 waves, <=128 regs
void fused_attn_mfma(const float* __restrict__ v,
                     const _Float16* __restrict__ Wqkv_pk,
                     const _Float16* __restrict__ Wp_pk,
                     const float* __restrict__ bp,
                     float* __restrict__ out,
                     int ntok)
{
    __shared__ __align__(16) _Float16 S[TM * QSTRIDE];   // 74,496 B

    const int tid   = threadIdx.x;
    const int lane  = tid & 63;
    const int wv_id = tid >> 6;      // wave 0..7
    const int l15   = lane & 15;
    const int quad  = lane >> 4;
    const int token0 = blockIdx.x * TM;
    int valid = ntok - token0; if (valid > TM) valid = TM;

    // GEMM1 n-tiles: pass0 = k-section + v-low (cols >= 256, no v-tile alias,
    // immediate writeback); pass1 = q-section + v-tail (writeback deferred).
    const int tiles0[3] = { 16 + 3 * wv_id, 17 + 3 * wv_id, 18 + 3 * wv_id };
    const int tiles1[3] = { 2 * wv_id, 2 * wv_id + 1, 40 + wv_id };

    const f16x8* wb  = (const f16x8*)Wqkv_pk + lane;
    const f16x8* wb2 = (const f16x8*)Wp_pk + lane;

    // ---- stage 0: v-tile global loads (guarded), pass0 weight prologue -----
    {
        const float4* src = (const float4*)(v + (size_t)token0 * DIMX);
        float4 t4[6];
#pragma unroll
        for (int i = 0; i < 6; ++i) {
            int u = tid + NTHREADS * i;       // 0..3071 float4 slots
            int m = u >> 6;
            t4[i] = (m < valid) ? src[u] : (float4){0.f, 0.f, 0.f, 0.f};
        }
        // fp32 -> f16 -> S cols [0,256) (v tile lives in the q-section)
#pragma unroll
        for (int i = 0; i < 6; ++i) {
            int u = tid + NTHREADS * i;
            int m = u >> 6;
            int c = (u & 63) * 4;
            f16x2 lo = pkrtz(t4[i].x, t4[i].y), hi = pkrtz(t4[i].z, t4[i].w);
            f16x4 b4 = { lo.x, lo.y, hi.x, hi.y };
            *(f16x4*)&S[m * QSTRIDE + c] = b4;
        }
    }
    f16x8 wA[3], wB[3];
#pragma unroll
    for (int j = 0; j < 3; ++j) wA[j] = wb[(size_t)(tiles0[j] * KT + 0) * 64];
#pragma unroll
    for (int j = 0; j < 3; ++j) wB[j] = wb[(size_t)(tiles0[j] * KT + 1) * 64];
    __syncthreads();   // b1: v tile visible

    // ---- GEMM1 pass0: 3 tiles x 3 tt, lead-2 weight prefetch ---------------
    f32x4 acc0[3][3];
#pragma unroll
    for (int j = 0; j < 3; ++j)
#pragma unroll
        for (int tt = 0; tt < 3; ++tt)
            acc0[j][tt] = (f32x4){0.f, 0.f, 0.f, 0.f};

#pragma unroll
    for (int kt = 0; kt < KT; ++kt) {
        f16x8 wC[3];
        if (kt < KT - 2) {
#pragma unroll
            for (int j = 0; j < 3; ++j)
                wC[j] = wb[(size_t)(tiles0[j] * KT + kt + 2) * 64];
        } else {
#pragma unroll
            for (int j = 0; j < 3; ++j) wC[j] = wB[j];
        }
        f16x8 vf[3];
#pragma unroll
        for (int tt = 0; tt < 3; ++tt)
            vf[tt] = *(const f16x8*)&S[(tt * 16 + l15) * QSTRIDE + kt * 32 + quad * 8];
#pragma unroll
        for (int j = 0; j < 3; ++j)
#pragma unroll
            for (int tt = 0; tt < 3; ++tt)
                acc0[j][tt] = __builtin_amdgcn_mfma_f32_16x16x32_f16(wA[j], vf[tt], acc0[j][tt], 0, 0, 0);
#pragma unroll
        for (int j = 0; j < 3; ++j) { wA[j] = wB[j]; wB[j] = wC[j]; }
    }

    // pass1 weight prologue (in flight during pass0 writeback)
    f16x8 pA[3], pB[3];
#pragma unroll
    for (int j = 0; j < 3; ++j) pA[j] = wb[(size_t)(tiles1[j] * KT + 0) * 64];
#pragma unroll
    for (int j = 0; j < 3; ++j) pB[j] = wb[(size_t)(tiles1[j] * KT + 1) * 64];

    // immediate writeback pass0 (cols >= 256; no alias with v tile)
#pragma unroll
    for (int j = 0; j < 3; ++j)
#pragma unroll
        for (int tt = 0; tt < 3; ++tt) {
            f16x2 a = pkrtz(acc0[j][tt][0], acc0[j][tt][1]);
            f16x2 b = pkrtz(acc0[j][tt][2], acc0[j][tt][3]);
            f16x4 p4 = { a.x, a.y, b.x, b.y };
            *(f16x4*)&S[(tt * 16 + l15) * QSTRIDE + tiles0[j] * 16 + quad * 4] = p4;
        }

    // ---- GEMM1 pass1 -------------------------------------------------------
    f32x4 acc1[3][3];
#pragma unroll
    for (int j = 0; j < 3; ++j)
#pragma unroll
        for (int tt = 0; tt < 3; ++tt)
            acc1[j][tt] = (f32x4){0.f, 0.f, 0.f, 0.f};

#pragma unroll
    for (int kt = 0; kt < KT; ++kt) {
        f16x8 pC[3];
        if (kt < KT - 2) {
#pragma unroll
            for (int j = 0; j < 3; ++j)
                pC[j] = wb[(size_t)(tiles1[j] * KT + kt + 2) * 64];
        } else {
#pragma unroll
            for (int j = 0; j < 3; ++j) pC[j] = pB[j];
        }
        f16x8 vf[3];
#pragma unroll
        for (int tt = 0; tt < 3; ++tt)
            vf[tt] = *(const f16x8*)&S[(tt * 16 + l15) * QSTRIDE + kt * 32 + quad * 8];
#pragma unroll
        for (int j = 0; j < 3; ++j)
#pragma unroll
            for (int tt = 0; tt < 3; ++tt)
                acc1[j][tt] = __builtin_amdgcn_mfma_f32_16x16x32_f16(pA[j], vf[tt], acc1[j][tt], 0, 0, 0);
#pragma unroll
        for (int j = 0; j < 3; ++j) { pA[j] = pB[j]; pB[j] = pC[j]; }
    }
    __syncthreads();   // b2: ALL v-tile reads done; q-section writable

    // deferred pass1 writeback
#pragma unroll
    for (int j = 0; j < 3; ++j)
#pragma unroll
        for (int tt = 0; tt < 3; ++tt) {
            f16x2 a = pkrtz(acc1[j][tt][0], acc1[j][tt][1]);
            f16x2 b = pkrtz(acc1[j][tt][2], acc1[j][tt][3]);
            f16x4 p4 = { a.x, a.y, b.x, b.y };
            *(f16x4*)&S[(tt * 16 + l15) * QSTRIDE + tiles1[j] * 16 + quad * 4] = p4;
        }

    // GEMM2 weight prologue (latency hides under barrier + attention)
    const int nt0 = 2 * wv_id;
    f16x8 wA2[2], wB2[2];
#pragma unroll
    for (int j = 0; j < 2; ++j) wA2[j] = wb2[(size_t)((nt0 + j) * KT + 0) * 64];
#pragma unroll
    for (int j = 0; j < 2; ++j) wB2[j] = wb2[(size_t)((nt0 + j) * KT + 1) * 64];
    __syncthreads();   // b3: q|k|vv complete in LDS

    // ---- attention: 8 threads/token (sub = head), thread-local softmax -----
    const int ta  = tid >> 3;         // token slot 0..63 (0..47 used)
    const int h   = tid & 7;          // head
    const bool act = (ta < TM);
    f16x8 xa0, xa1, xa2, xa3;
    if (act) {
        const float scale = 0.17677669529663687f;  // 32^-0.5
        const _Float16* qrow  = &S[ta * QSTRIDE + h * HD];
        const _Float16* kbase = &S[ta * QSTRIDE + 256];
        const _Float16* vbase = &S[ta * QSTRIDE + 512];

        f16x8 q0 = *(const f16x8*)(qrow);
        f16x8 q1 = *(const f16x8*)(qrow + 8);
        f16x8 q2 = *(const f16x8*)(qrow + 16);
        f16x8 q3 = *(const f16x8*)(qrow + 24);

        float logits[NH];
#pragma unroll
        for (int g = 0; g < NH; ++g) {
            const _Float16* kg = kbase + g * HD;
            f16x8 p = q0 * *(const f16x8*)(kg);
            p += q1 * *(const f16x8*)(kg + 8);
            p += q2 * *(const f16x8*)(kg + 16);
            p += q3 * *(const f16x8*)(kg + 24);
            f16x4 r4 = __builtin_shufflevector(p, p, 0, 1, 2, 3)
                     + __builtin_shufflevector(p, p, 4, 5, 6, 7);
            f16x2 r2 = __builtin_shufflevector(r4, r4, 0, 1)
                     + __builtin_shufflevector(r4, r4, 2, 3);
            logits[g] = ((float)r2.x + (float)r2.y) * scale;
        }
        float mx = logits[0];
#pragma unroll
        for (int g = 1; g < NH; ++g) mx = fmaxf(mx, logits[g]);
        float se = 0.f;
#pragma unroll
        for (int g = 0; g < NH; ++g) { logits[g] = __expf(logits[g] - mx); se += logits[g]; }
        float inv = 1.f / se;

        xa0 = (f16x8)(_Float16)0.f; xa1 = (f16x8)(_Float16)0.f;
        xa2 = (f16x8)(_Float16)0.f; xa3 = (f16x8)(_Float16)0.f;
#pragma unroll
        for (int g = 0; g < NH; ++g) {
            _Float16 ph = (_Float16)(logits[g] * inv);
            f16x8 pw = { ph, ph, ph, ph, ph, ph, ph, ph };
            const _Float16* vg = vbase + g * HD;
            xa0 += pw * *(const f16x8*)(vg);
            xa1 += pw * *(const f16x8*)(vg + 8);
            xa2 += pw * *(const f16x8*)(vg + 16);
            xa3 += pw * *(const f16x8*)(vg + 24);
        }
    }
    __syncthreads();   // b4: all q/k reads done; safe to overwrite q with x
    if (act) {
        _Float16* xrow = &S[ta * QSTRIDE + h * HD];
        *(f16x8*)(xrow)      = xa0;
        *(f16x8*)(xrow + 8)  = xa1;
        *(f16x8*)(xrow + 16) = xa2;
        *(f16x8*)(xrow + 24) = xa3;
    }
    __syncthreads();   // b5: x tile complete

    // ---- GEMM2: out = x @ Wp + bp; wave w owns n-tiles {2w, 2w+1} ----------
    {
        f32x4 acc2[2][3];
#pragma unroll
        for (int j = 0; j < 2; ++j)
#pragma unroll
            for (int tt = 0; tt < 3; ++tt)
                acc2[j][tt] = (f32x4){0.f, 0.f, 0.f, 0.f};

#pragma unroll
        for (int kt = 0; kt < KT; ++kt) {
            f16x8 wC2[2];
            if (kt < KT - 2) {
#pragma unroll
                for (int j = 0; j < 2; ++j)
                    wC2[j] = wb2[(size_t)((nt0 + j) * KT + kt + 2) * 64];
            } else {
#pragma unroll
                for (int j = 0; j < 2; ++j) wC2[j] = wB2[j];
            }
            f16x8 xf[3];
#pragma unroll
            for (int tt = 0; tt < 3; ++tt)
                xf[tt] = *(const f16x8*)&S[(tt * 16 + l15) * QSTRIDE + kt * 32 + quad * 8];
#pragma unroll
            for (int j = 0; j < 2; ++j)
#pragma unroll
                for (int tt = 0; tt < 3; ++tt)
                    acc2[j][tt] = __builtin_amdgcn_mfma_f32_16x16x32_f16(wA2[j], xf[tt], acc2[j][tt], 0, 0, 0);
#pragma unroll
            for (int j = 0; j < 2; ++j) { wA2[j] = wB2[j]; wB2[j] = wC2[j]; }
        }

#pragma unroll
        for (int j = 0; j < 2; ++j) {
            f32x4 b = *(const f32x4*)&bp[(nt0 + j) * 16 + quad * 4];
#pragma unroll
            for (int tt = 0; tt < 3; ++tt) {
                int row = token0 + tt * 16 + l15;
                if (row < ntok) {
                    f32x4 o = acc2[j][tt] + b;
                    *(f32x4*)&out[(size_t)row * DIMX + (nt0 + j) * 16 + quad * 4] = o;
                }
            }
        }
    }
}

extern "C" void kernel_launch(void* const* d_in, const int* in_sizes, int n_in,
                              void* d_out, int out_size, void* d_ws, size_t ws_size,
                              hipStream_t stream) {
    const float* v  = (const float*)d_in[0];
    const float* Wq = (const float*)d_in[1];
    const float* Wk = (const float*)d_in[2];
    const float* Wv = (const float*)d_in[3];
    const float* Wp = (const float*)d_in[4];
    const float* bp = (const float*)d_in[5];
    float* out = (float*)d_out;

    _Float16* pk = (_Float16*)d_ws;                // 32768 frags * 16 B = 512 KB
    const _Float16* Wqkv_pk = pk;                  // 24576 frags
    const _Float16* Wp_pk   = pk + (size_t)24576 * 8;

    pack_weights<<<256, 128, 0, stream>>>(Wq, Wk, Wv, Wp, pk);

    const int ntokens = in_sizes[0] / DIMX;        // 65536
    const int nblk = (ntokens + TM - 1) / TM;      // 1366
    fused_attn_mfma<<<nblk, NTHREADS, 0, stream>>>(v, Wqkv_pk, Wp_pk, bp, out, ntokens);
}